// Round 1
// baseline (212.578 us; speedup 1.0000x reference)
//
#include <hip/hip_runtime.h>
#include <math.h>

constexpr int kH = 64, kW = 128, kB = 2, kS = 4;
constexpr int kNP = kH * kW;          // 8192 points per set
constexpr int kPairs = kB * kS;       // 8
constexpr int kDirs = kPairs * 2;     // 16 (pair, direction)
constexpr float kBig = 1e9f;
constexpr float kPi = 3.14159265358979323846f;
constexpr float kFovUp = 3.0f * kPi / 180.0f;
constexpr float kFovDown = -25.0f * kPi / 180.0f;

// NN tiling
constexpr int NN_BLOCK = 256;         // 4 waves
constexpr int NN_Q = 8;               // queries per thread (registers)
constexpr int QPB = NN_BLOCK * NN_Q;  // 2048 queries per block
constexpr int NBQ = kNP / QPB;        // 4 query-blocks per dir
constexpr int NC = 8;                 // candidate chunks
constexpr int CHUNK = kNP / NC;       // 1024 candidates per chunk

// ws layout (float offsets)
// q4     : [kDirs][kNP] float4  -> 524288 floats @ 0
// db4    : [kDirs][kNP] float4  -> 524288 floats @ 524288
// qmask  : [kDirs][kNP] float   -> 131072 floats @ 1048576
// partial: [kDirs][NC][kNP]     -> 1048576 floats @ 1179648
// mval   : [kDirs]              -> 16 floats @ 2228224
constexpr size_t OFF_DB4 = 524288;
constexpr size_t OFF_QM = 1048576;
constexpr size_t OFF_PART = 1179648;
constexpr size_t OFF_MVAL = 2228224;

__global__ __launch_bounds__(256) void prep_kernel(
    const float* __restrict__ rv, const float* __restrict__ tgt,
    float4* __restrict__ q4, float4* __restrict__ db4,
    float* __restrict__ qmask) {
  int idx = blockIdx.x * 256 + threadIdx.x;   // [0, kPairs*kNP)
  int p = idx >> 13;                          // / 8192
  int k = idx & (kNP - 1);
  int h = k >> 7;                             // / 128
  int w = k & 127;

  float r = rv[idx];
  float pitch = (1.0f - (h + 0.5f) * (1.0f / kH)) * (kFovUp - kFovDown) + kFovDown;
  float yaw = -(((w + 0.5f) * (1.0f / kW)) * 2.0f - 1.0f) * kPi;
  float cp = cosf(pitch), sp = sinf(pitch);
  float cy = cosf(yaw), sy = sinf(yaw);
  float px = r * cp * cy, py = r * cp * sy, pz = r * sp;
  float mo = (r > 0.0f) ? 1.0f : 0.0f;

  const float* tb = tgt + (size_t)p * 4 * kNP;
  float mt = (tb[k] > 0.0f) ? 1.0f : 0.0f;
  float tx = tb[kNP + k], ty = tb[2 * kNP + k], tz = tb[3 * kNP + k];

  float no = px * px + py * py + pz * pz;
  float nt = tx * tx + ty * ty + tz * tz;

  int d0 = p * 2, d1 = p * 2 + 1;
  // direction 0: queries = rv points (mask mo), database = target points (penalty via mt)
  q4[d0 * kNP + k] = make_float4(px, py, pz, no);
  qmask[d0 * kNP + k] = mo;
  db4[d0 * kNP + k] = make_float4(-2.0f * tx, -2.0f * ty, -2.0f * tz,
                                  nt + kBig * (1.0f - mt));
  // direction 1: queries = target points (mask mt), database = rv points
  q4[d1 * kNP + k] = make_float4(tx, ty, tz, nt);
  qmask[d1 * kNP + k] = mt;
  db4[d1 * kNP + k] = make_float4(-2.0f * px, -2.0f * py, -2.0f * pz,
                                  no + kBig * (1.0f - mo));
}

__global__ __launch_bounds__(NN_BLOCK) void nn_kernel(
    const float4* __restrict__ q4, const float4* __restrict__ db4,
    float* __restrict__ partial) {
  int bid = blockIdx.x;
  int d = bid / (NBQ * NC);
  int rem = bid % (NBQ * NC);
  int qb = rem / NC;
  int ch = rem % NC;
  int t = threadIdx.x;

  const float4* q = q4 + d * kNP + qb * QPB;
  const float4* db = db4 + d * kNP + ch * CHUNK;

  float qx[NN_Q], qy[NN_Q], qz[NN_Q], mn[NN_Q];
#pragma unroll
  for (int i = 0; i < NN_Q; ++i) {
    float4 v = q[t + i * NN_BLOCK];
    qx[i] = v.x; qy[i] = v.y; qz[i] = v.z;
    mn[i] = 3.0e38f;
  }

#pragma unroll 4
  for (int j = 0; j < CHUNK; ++j) {
    float4 c = db[j];   // wave-uniform -> scalar load expected
#pragma unroll
    for (int i = 0; i < NN_Q; ++i) {
      float v = fmaf(qx[i], c.x, fmaf(qy[i], c.y, fmaf(qz[i], c.z, c.w)));
      mn[i] = fminf(mn[i], v);
    }
  }

  float* out = partial + (size_t)(d * NC + ch) * kNP + qb * QPB;
#pragma unroll
  for (int i = 0; i < NN_Q; ++i) out[t + i * NN_BLOCK] = mn[i];
}

__global__ __launch_bounds__(256) void fin_kernel(
    const float4* __restrict__ q4, const float* __restrict__ qmask,
    const float* __restrict__ partial, float* __restrict__ mval) {
  int d = blockIdx.x;
  int t = threadIdx.x;
  float wsum = 0.0f, msum = 0.0f;
  for (int k = t; k < kNP; k += 256) {
    float mn = 3.0e38f;
#pragma unroll
    for (int c = 0; c < NC; ++c)
      mn = fminf(mn, partial[(size_t)(d * NC + c) * kNP + k]);
    float4 qv = q4[d * kNP + k];
    float qm = qmask[d * kNP + k];
    wsum += qm * (qv.w + mn);
    msum += qm;
  }
  // wave64 reduce
#pragma unroll
  for (int off = 32; off; off >>= 1) {
    wsum += __shfl_down(wsum, off);
    msum += __shfl_down(msum, off);
  }
  __shared__ float sw[4], sm[4];
  int wave = t >> 6;
  if ((t & 63) == 0) { sw[wave] = wsum; sm[wave] = msum; }
  __syncthreads();
  if (t == 0) {
    float ws_ = sw[0] + sw[1] + sw[2] + sw[3];
    float ms_ = sm[0] + sm[1] + sm[2] + sm[3];
    mval[d] = ws_ / fmaxf(ms_, 1.0f);
  }
}

__global__ void comb_kernel(const float* __restrict__ mval,
                            float* __restrict__ out) {
  if (threadIdx.x == 0 && blockIdx.x == 0) {
    float tens[kS][kB];
    for (int b = 0; b < kB; ++b)
      for (int s = 0; s < kS; ++s) {
        int p = b * kS + s;
        tens[s][b] = mval[2 * p] + mval[2 * p + 1];
      }
    for (int s = 0; s < kS; ++s) {
      float acc = 0.0f;
      for (int b = 0; b < kB; ++b) {
        out[kS + s * kB + b] = tens[s][b];
        acc += tens[s][b];
      }
      out[s] = acc * (1.0f / kB);
    }
  }
}

extern "C" void kernel_launch(void* const* d_in, const int* in_sizes, int n_in,
                              void* d_out, int out_size, void* d_ws, size_t ws_size,
                              hipStream_t stream) {
  const float* rv = (const float*)d_in[0];
  const float* tgt = (const float*)d_in[1];
  float* ws = (float*)d_ws;
  float4* q4 = (float4*)ws;
  float4* db4 = (float4*)(ws + OFF_DB4);
  float* qmask = ws + OFF_QM;
  float* partial = ws + OFF_PART;
  float* mval = ws + OFF_MVAL;
  float* out = (float*)d_out;

  hipLaunchKernelGGL(prep_kernel, dim3(kPairs * kNP / 256), dim3(256), 0, stream,
                     rv, tgt, q4, db4, qmask);
  hipLaunchKernelGGL(nn_kernel, dim3(kDirs * NBQ * NC), dim3(NN_BLOCK), 0, stream,
                     q4, db4, partial);
  hipLaunchKernelGGL(fin_kernel, dim3(kDirs), dim3(256), 0, stream,
                     q4, qmask, partial, mval);
  hipLaunchKernelGGL(comb_kernel, dim3(1), dim3(64), 0, stream, mval, out);
}

// Round 2
// 159.089 us; speedup vs baseline: 1.3362x; 1.3362x over previous
//
#include <hip/hip_runtime.h>
#include <math.h>

constexpr int kH = 64, kW = 128, kB = 2, kS = 4;
constexpr int kNP = kH * kW;          // 8192 points per set
constexpr int kPairs = kB * kS;       // 8
constexpr int kDirs = kPairs * 2;     // 16 (pair, direction)
constexpr float kBig = 1e9f;
constexpr float kPi = 3.14159265358979323846f;
constexpr float kFovUp = 3.0f * kPi / 180.0f;
constexpr float kFovDown = -25.0f * kPi / 180.0f;

// NN tiling
constexpr int NN_BLOCK = 256;         // 4 waves
constexpr int NN_Q = 8;               // queries per thread (registers)
constexpr int QPB = NN_BLOCK * NN_Q;  // 2048 queries per block
constexpr int NBQ = kNP / QPB;        // 4 query-blocks per dir
constexpr int NC = 16;                // candidate chunks -> 1024 blocks total
constexpr int CHUNK = kNP / NC;       // 512 candidates per chunk
constexpr int CPAIRS = CHUNK / 2;     // 256 packed pairs per chunk

// ws layout (float offsets)
// q4    : [kDirs][kNP] float4   -> 524288 floats @ 0
// db2   : [kDirs][kNP] float4   -> 524288 floats @ 524288  (pair-interleaved)
// qmask : [kDirs][kNP] float    -> 131072 floats @ 1048576
// minarr: [kDirs][kNP] uint     -> 131072 @ 1179648
// accum : [kDirs][2] float      -> 32 @ 1310720
constexpr size_t OFF_DB2 = 524288;
constexpr size_t OFF_QM = 1048576;
constexpr size_t OFF_MIN = 1179648;
constexpr size_t OFF_ACC = 1310720;

typedef float v2f __attribute__((ext_vector_type(2)));

__device__ __forceinline__ v2f pk_fma(v2f a, v2f b, v2f c) {
  v2f d;
  asm("v_pk_fma_f32 %0, %1, %2, %3" : "=v"(d) : "v"(a), "v"(b), "v"(c));
  return d;
}

__global__ __launch_bounds__(256) void prep_kernel(
    const float* __restrict__ rv, const float* __restrict__ tgt,
    float4* __restrict__ q4, float* __restrict__ dbf,
    float* __restrict__ qmask, unsigned* __restrict__ minarr,
    float* __restrict__ accum) {
  int idx = blockIdx.x * 256 + threadIdx.x;   // [0, kPairs*kNP)
  int p = idx >> 13;
  int k = idx & (kNP - 1);
  int h = k >> 7;
  int w = k & 127;

  float r = rv[idx];
  float pitch = (1.0f - (h + 0.5f) * (1.0f / kH)) * (kFovUp - kFovDown) + kFovDown;
  float yaw = -(((w + 0.5f) * (1.0f / kW)) * 2.0f - 1.0f) * kPi;
  float cp = cosf(pitch), sp = sinf(pitch);
  float cy = cosf(yaw), sy = sinf(yaw);
  float px = r * cp * cy, py = r * cp * sy, pz = r * sp;
  float mo = (r > 0.0f) ? 1.0f : 0.0f;

  const float* tb = tgt + (size_t)p * 4 * kNP;
  float mt = (tb[k] > 0.0f) ? 1.0f : 0.0f;
  float tx = tb[kNP + k], ty = tb[2 * kNP + k], tz = tb[3 * kNP + k];

  float no = px * px + py * py + pz * pz;
  float nt = tx * tx + ty * ty + tz * tz;

  int d0 = p * 2, d1 = p * 2 + 1;
  // queries
  q4[d0 * kNP + k] = make_float4(px, py, pz, no);
  qmask[d0 * kNP + k] = mo;
  q4[d1 * kNP + k] = make_float4(tx, ty, tz, nt);
  qmask[d1 * kNP + k] = mt;

  // databases, pair-interleaved: pair jp occupies 8 floats:
  // [x_e,x_o,y_e,y_o,z_e,z_o,w_e,w_o]
  int jp = k >> 1, lane = k & 1;
  float ct = nt + kBig * (1.0f - mt);
  float* b0 = dbf + ((size_t)d0 * kNP * 4 + (size_t)jp * 8);
  b0[0 + lane] = -2.0f * tx;
  b0[2 + lane] = -2.0f * ty;
  b0[4 + lane] = -2.0f * tz;
  b0[6 + lane] = ct;
  float co = no + kBig * (1.0f - mo);
  float* b1 = dbf + ((size_t)d1 * kNP * 4 + (size_t)jp * 8);
  b1[0 + lane] = -2.0f * px;
  b1[2 + lane] = -2.0f * py;
  b1[4 + lane] = -2.0f * pz;
  b1[6 + lane] = co;

  minarr[d0 * kNP + k] = 0xFFFFFFFFu;
  minarr[d1 * kNP + k] = 0xFFFFFFFFu;
  if (idx < 2 * kDirs) accum[idx] = 0.0f;
}

__global__ __launch_bounds__(NN_BLOCK, 4) void nn_kernel(
    const float4* __restrict__ q4, const float4* __restrict__ db2,
    unsigned* __restrict__ minarr) {
  int bid = blockIdx.x;
  int d = bid >> 6;            // / (NBQ*NC) = 64
  int rem = bid & 63;
  int qb = rem >> 4;           // / NC
  int ch = rem & (NC - 1);
  int t = threadIdx.x;

  const float4* q = q4 + (size_t)d * kNP + qb * QPB;
  const float4* db = db2 + (size_t)d * kNP + ch * CHUNK;  // float4 units

  v2f qx[NN_Q], qy[NN_Q], qz[NN_Q], mn[NN_Q];
#pragma unroll
  for (int i = 0; i < NN_Q; ++i) {
    float4 v = q[t + i * NN_BLOCK];
    qx[i] = (v2f){v.x, v.x};
    qy[i] = (v2f){v.y, v.y};
    qz[i] = (v2f){v.z, v.z};
    mn[i] = (v2f){3.0e38f, 3.0e38f};
  }

#pragma unroll 2
  for (int jp = 0; jp < CPAIRS; ++jp) {
    int i0 = 2 * jp;
    asm volatile("" : "+v"(i0));  // keep address in VGPR -> vector load (data lands in VGPRs)
    float4 A = db[i0];            // {x_e, x_o, y_e, y_o}
    float4 B = db[i0 + 1];        // {z_e, z_o, w_e, w_o}
    v2f cx = (v2f){A.x, A.y};
    v2f cyv = (v2f){A.z, A.w};
    v2f cz = (v2f){B.x, B.y};
    v2f cw = (v2f){B.z, B.w};
#pragma unroll
    for (int i = 0; i < NN_Q; ++i) {
      v2f v = pk_fma(qz[i], cz, cw);
      v = pk_fma(qy[i], cyv, v);
      v = pk_fma(qx[i], cx, v);
      mn[i].x = fminf(mn[i].x, v.x);
      mn[i].y = fminf(mn[i].y, v.y);
    }
  }

  unsigned* ma = minarr + (size_t)d * kNP + qb * QPB;
#pragma unroll
  for (int i = 0; i < NN_Q; ++i) {
    float f = fminf(mn[i].x, mn[i].y);
    unsigned b = __float_as_uint(f);
    unsigned e = (b & 0x80000000u) ? ~b : (b | 0x80000000u);
    atomicMin(&ma[t + i * NN_BLOCK], e);
  }
}

__global__ __launch_bounds__(256) void fin_kernel(
    const float4* __restrict__ q4, const float* __restrict__ qmask,
    const unsigned* __restrict__ minarr, float* __restrict__ accum) {
  int d = blockIdx.x >> 3;
  int sub = blockIdx.x & 7;
  int t = threadIdx.x;
  float wsum = 0.0f, msum = 0.0f;
#pragma unroll
  for (int i = 0; i < 4; ++i) {
    int k = sub * 1024 + i * 256 + t;
    unsigned u = minarr[(size_t)d * kNP + k];
    unsigned b = (u & 0x80000000u) ? (u ^ 0x80000000u) : ~u;
    float mnv = __uint_as_float(b);
    float4 qv = q4[(size_t)d * kNP + k];
    float qm = qmask[(size_t)d * kNP + k];
    wsum += qm * (qv.w + mnv);
    msum += qm;
  }
#pragma unroll
  for (int off = 32; off; off >>= 1) {
    wsum += __shfl_down(wsum, off);
    msum += __shfl_down(msum, off);
  }
  __shared__ float sw[4], sm[4];
  int wave = t >> 6;
  if ((t & 63) == 0) { sw[wave] = wsum; sm[wave] = msum; }
  __syncthreads();
  if (t == 0) {
    atomicAdd(&accum[2 * d], sw[0] + sw[1] + sw[2] + sw[3]);
    atomicAdd(&accum[2 * d + 1], sm[0] + sm[1] + sm[2] + sm[3]);
  }
}

__global__ void comb_kernel(const float* __restrict__ accum,
                            float* __restrict__ out) {
  if (threadIdx.x == 0 && blockIdx.x == 0) {
    float mval[kDirs];
    for (int d = 0; d < kDirs; ++d)
      mval[d] = accum[2 * d] / fmaxf(accum[2 * d + 1], 1.0f);
    for (int s = 0; s < kS; ++s) {
      float acc = 0.0f;
      for (int b = 0; b < kB; ++b) {
        int p = b * kS + s;
        float tens = mval[2 * p] + mval[2 * p + 1];
        out[kS + s * kB + b] = tens;
        acc += tens;
      }
      out[s] = acc * (1.0f / kB);
    }
  }
}

extern "C" void kernel_launch(void* const* d_in, const int* in_sizes, int n_in,
                              void* d_out, int out_size, void* d_ws, size_t ws_size,
                              hipStream_t stream) {
  const float* rv = (const float*)d_in[0];
  const float* tgt = (const float*)d_in[1];
  float* ws = (float*)d_ws;
  float4* q4 = (float4*)ws;
  float* dbf = ws + OFF_DB2;
  float4* db2 = (float4*)dbf;
  float* qmask = ws + OFF_QM;
  unsigned* minarr = (unsigned*)(ws + OFF_MIN);
  float* accum = ws + OFF_ACC;
  float* out = (float*)d_out;

  hipLaunchKernelGGL(prep_kernel, dim3(kPairs * kNP / 256), dim3(256), 0, stream,
                     rv, tgt, q4, dbf, qmask, minarr, accum);
  hipLaunchKernelGGL(nn_kernel, dim3(kDirs * NBQ * NC), dim3(NN_BLOCK), 0, stream,
                     q4, db2, minarr);
  hipLaunchKernelGGL(fin_kernel, dim3(kDirs * 8), dim3(256), 0, stream,
                     q4, qmask, minarr, accum);
  hipLaunchKernelGGL(comb_kernel, dim3(1), dim3(64), 0, stream, accum, out);
}